// Round 6
// baseline (529.671 us; speedup 1.0000x reference)
//
#include <hip/hip_runtime.h>
#include <hip/hip_fp16.h>

// RandDCGRUCell on MI355X.
// B=64, N=2000, IN_DIM=2, U=64, D=66, NSUP=2, K=2, M=5.
// R17: gather reverted to R15 form (R16's 8-deep+pad regressed: 65->68.5,
// occ 64->42%; three gather variants all ~65-68us => external L2/TCP
// line-rate bound, stop tuning it). New: k_projm T14 async-stage split -
// stage-1 W prefetched to REGISTERS at kernel start (in flight with
// stage-0 fill + A-loads), mid-kernel refill becomes pure ds_write.
// R15: one row per wave64, scalarized ELL walk (s_load cols/vals).
// R13: k_projm 512-thr node-parallel, A-frags in regs across stages.

#define N_NODES 2000
#define BATCH   64
#define MMATS   5
#define ELLW    128
#define NSTRIDE 1536            // dwords per (cc, n): 48 kb * 32
#define SLICE_DW ((size_t)N_NODES * NSTRIDE)   // dwords per chunk (3,072,000)
#define PLANE_OFF(p) ((p)*288)  // dword offset of plane p within (cc,n)

typedef __half h16;
typedef _Float16 f16x8 __attribute__((ext_vector_type(8)));
typedef float    f32x4 __attribute__((ext_vector_type(4)));
typedef unsigned int u32x4 __attribute__((ext_vector_type(4)));

__device__ __forceinline__ __half2 f2h2(float a, float b) {
  __half2 r; r.x = __float2half_rn(a); r.y = __float2half_rn(b); return r;
}
__device__ __forceinline__ unsigned int packh(float a, float b) {
  __half2 h = f2h2(a, b);
  return __builtin_bit_cast(unsigned int, h);
}
__device__ __forceinline__ float2 u2f2(unsigned int u) {
  return __half22float2(__builtin_bit_cast(__half2, u));
}
__device__ __forceinline__ float h16lo(unsigned int u) {
  __half h = __builtin_bit_cast(__half2, u).x;
  return __half2float(h);
}
__device__ __forceinline__ float fexp2(float x) {
#if __has_builtin(__builtin_amdgcn_exp2f)
  return __builtin_amdgcn_exp2f(x);
#else
  return exp2f(x);
#endif
}
__device__ __forceinline__ float frcp(float x) {
#if __has_builtin(__builtin_amdgcn_rcpf)
  return __builtin_amdgcn_rcpf(x);
#else
  return 1.f/x;
#endif
}
#define LOG2E 1.44269504088896f
__device__ __forceinline__ float fsigmoid(float x) {
  return frcp(1.f + fexp2(-LOG2E*x));
}
__device__ __forceinline__ float ftanh(float x) {
  return 1.f - 2.f*frcp(1.f + fexp2((2.f*LOG2E)*x));
}

// 4-dword + tail-half elementwise FMA: acc[i] += v * half2(dword_i)
__device__ __forceinline__ void fma4t(float v, u32x4 q, unsigned int te,
                                      float2* acc, float& acct) {
  float2 f;
  f = u2f2(q[0]); acc[0].x = fmaf(v,f.x,acc[0].x); acc[0].y = fmaf(v,f.y,acc[0].y);
  f = u2f2(q[1]); acc[1].x = fmaf(v,f.x,acc[1].x); acc[1].y = fmaf(v,f.y,acc[1].y);
  f = u2f2(q[2]); acc[2].x = fmaf(v,f.x,acc[2].x); acc[2].y = fmaf(v,f.y,acc[2].y);
  f = u2f2(q[3]); acc[3].x = fmaf(v,f.x,acc[3].x); acc[3].y = fmaf(v,f.y,acc[3].y);
  acct = fmaf(v, h16lo(te), acct);
}

// ---------------- weights: fragment-order swizzled fp16 W -----------
// Wz[((ot*12 + k0)*64 + lane)*8 + j] = W[k][o], k = k0*32 + (lane>>4)*8 + j,
// o = ot*16 + (lane&15); k = 72p + d (plane-major), d<66 valid, k>=360 -> 0.
__global__ __launch_bounds__(256) void k_weights(
    const float* __restrict__ mu_w_ru, const float* __restrict__ ls_w_ru, const float* __restrict__ eps_w_ru,
    const float* __restrict__ mu_b_ru, const float* __restrict__ ls_b_ru, const float* __restrict__ eps_b_ru,
    const float* __restrict__ mu_w_c,  const float* __restrict__ ls_w_c,  const float* __restrict__ eps_w_c,
    const float* __restrict__ mu_b_c,  const float* __restrict__ ls_b_c,  const float* __restrict__ eps_b_c,
    h16* __restrict__ Wzru, float* __restrict__ bru,
    h16* __restrict__ Wzc,  float* __restrict__ bc)
{
  int idx = blockIdx.x*256 + threadIdx.x;
  const int n_ru = 8*12*64*8;   // 49152
  const int n_c  = 4*12*64*8;   // 24576
  if (idx < n_ru) {
    int j = idx & 7, ln = (idx >> 3) & 63, rest = idx >> 9;
    int k = (rest % 12)*32 + (ln >> 4)*8 + j;
    int o = (rest / 12)*16 + (ln & 15);
    float wv = 0.f;
    if (k < 360) {
      int p = k/72, d = k - p*72;
      if (d < 66) {
        int r = (d*MMATS + p)*128 + o;
        wv = mu_w_ru[r] + expf(ls_w_ru[r]) * eps_w_ru[r];
      }
    }
    Wzru[idx] = __float2half_rn(wv);
  } else if (idx < n_ru + n_c) {
    int i = idx - n_ru;
    int j = i & 7, ln = (i >> 3) & 63, rest = i >> 9;
    int k = (rest % 12)*32 + (ln >> 4)*8 + j;
    int o = (rest / 12)*16 + (ln & 15);
    float wv = 0.f;
    if (k < 360) {
      int p = k/72, d = k - p*72;
      if (d < 66) {
        int r = (d*MMATS + p)*64 + o;
        wv = mu_w_c[r] + expf(ls_w_c[r]) * eps_w_c[r];
      }
    }
    Wzc[i] = __float2half_rn(wv);
  } else if (idx < n_ru + n_c + 128) {
    int i = idx - n_ru - n_c;
    bru[i] = mu_b_ru[i] + expf(ls_b_ru[i]) * eps_b_ru[i];
  } else if (idx < n_ru + n_c + 128 + 64) {
    int i = idx - n_ru - n_c - 128;
    bc[i] = mu_b_c[i] + expf(ls_b_c[i]) * eps_b_c[i];
  }
}

// ---------------- ELL build (order within row irrelevant for a sum) --
__global__ __launch_bounds__(256) void k_ell(
    const float* __restrict__ supp, int* __restrict__ cols,
    float* __restrict__ vals, int* __restrict__ cnt)
{
  int j = blockIdx.x*256 + threadIdx.x;
  if (j >= N_NODES) return;
  int n = blockIdx.y, s = blockIdx.z;
  int r = s*N_NODES + n;
  float v = supp[(size_t)r*N_NODES + j];
  if (v != 0.f) {
    int p = atomicAdd(cnt + r, 1);
    if (p < ELLW) {
      cols[(size_t)r*ELLW + p] = j;
      vals[(size_t)r*ELLW + p] = v;
    }
  }
}

// ---------------- build x0 plane (p=0) + zero pad blocks -------------
// XA micro-block layout per (cc,n): [48kb][8bs][8k] halfs (1536 dwords).
__global__ __launch_bounds__(256) void k_build0(
    const float* __restrict__ inp, const float* __restrict__ hx,
    const h16* __restrict__ VALr, unsigned int* __restrict__ XAu, int mode)
{
  const int n = blockIdx.x;
  const int g = threadIdx.x >> 5, tt = threadIdx.x & 31;
  const int b = g*8 + (tt >> 2);
  unsigned int* dst = XAu + (size_t)g*SLICE_DW + (size_t)n*NSTRIDE;
  #pragma unroll
  for (int kb = 0; kb < 9; ++kb) {
    int d0 = kb*8 + 2*(tt & 3);
    float v[2];
    #pragma unroll
    for (int q = 0; q < 2; ++q) {
      int d = d0 + q;
      float x = 0.f;
      if (d < 2) {
        x = inp[(size_t)b*(N_NODES*2) + n*2 + d];
      } else if (d < 66) {
        x = hx[(size_t)b*(N_NODES*64) + n*64 + (d-2)];
        if (mode == 1) x *= __half2float(VALr[(size_t)n*8192 + b*128 + (d-2)]);
      }
      v[q] = x;
    }
    dst[kb*32 + tt] = packh(v[0], v[1]);
  }
  dst[45*32 + tt] = 0u;  // pad kbs 45..47 (k in [360,384))
  dst[46*32 + tt] = 0u;
  dst[47*32 + tt] = 0u;
}

// ---------------- SpMM: plane(1+2s) = S_s @ plane0 -------------------
// One row per wave64. Scalar (SGPR) ELL walk; lane owns dwords
// [4L,4L+4) + half of dword 256+(L>>1). 2-deep VMEM prefetch.
__global__ __launch_bounds__(256) void k_spmm(
    unsigned int* __restrict__ XAu, const int* __restrict__ cols,
    const float* __restrict__ vals, const int* __restrict__ cnt)
{
  const int cc = blockIdx.x;
  const int lane = threadIdx.x & 63;
  const int rr = blockIdx.y*4 + (threadIdx.x >> 6);
  const int r  = __builtin_amdgcn_readfirstlane(rr);
  const int s  = (r >= N_NODES) ? 1 : 0;
  const int n  = r - s*N_NODES;
  int c = cnt[r]; if (c > ELLW) c = ELLW;
  const int*   cp = cols + (size_t)r*ELLW;
  const float* vp = vals + (size_t)r*ELLW;
  const unsigned int* slice = XAu + (size_t)cc*SLICE_DW;   // plane 0 offset 0
  const int sh = (lane & 1) * 16;          // tail half select
  float2 acc[4];
  float  acct = 0.f;
  #pragma unroll
  for (int i = 0; i < 4; ++i) acc[i] = make_float2(0.f, 0.f);
  if (c > 0) {
    int j0 = cp[0];
    const unsigned int* p = slice + (size_t)j0*NSTRIDE;
    u32x4 q = *(const u32x4*)(p + lane*4);
    unsigned int te = p[256 + (lane >> 1)] >> sh;
    for (int k = 0; k < c; ++k) {
      float v = vp[k];
      int kn = (k + 1 < c) ? k + 1 : k;
      int jn = cp[kn];
      const unsigned int* pn = slice + (size_t)jn*NSTRIDE;
      u32x4 nq = *(const u32x4*)(pn + lane*4);
      unsigned int nte = pn[256 + (lane >> 1)] >> sh;
      fma4t(v, q, te, acc, acct);
      q = nq; te = nte;
    }
  }
  unsigned int* dp = XAu + (size_t)cc*SLICE_DW + (size_t)n*NSTRIDE
                   + PLANE_OFF(1 + 2*s);
  u32x4 w;
  w[0] = packh(acc[0].x,acc[0].y); w[1] = packh(acc[1].x,acc[1].y);
  w[2] = packh(acc[2].x,acc[2].y); w[3] = packh(acc[3].x,acc[3].y);
  *(u32x4*)(dp + lane*4) = w;
  ((h16*)dp)[512 + lane] = __float2half_rn(acct);
}

// ---------------- Chebyshev: plane(2+2s) = 2*S_s@plane(1+2s) - plane0 -
__global__ __launch_bounds__(256) void k_cheb(
    unsigned int* __restrict__ XAu, const int* __restrict__ cols,
    const float* __restrict__ vals, const int* __restrict__ cnt)
{
  const int cc = blockIdx.x;
  const int lane = threadIdx.x & 63;
  const int rr = blockIdx.y*4 + (threadIdx.x >> 6);
  const int r  = __builtin_amdgcn_readfirstlane(rr);
  const int s  = (r >= N_NODES) ? 1 : 0;
  const int n  = r - s*N_NODES;
  int c = cnt[r]; if (c > ELLW) c = ELLW;
  const int*   cp = cols + (size_t)r*ELLW;
  const float* vp = vals + (size_t)r*ELLW;
  const unsigned int* slice = XAu + (size_t)cc*SLICE_DW + PLANE_OFF(1 + 2*s);
  const int sh = (lane & 1) * 16;
  float2 acc[4];
  float  acct = 0.f;
  #pragma unroll
  for (int i = 0; i < 4; ++i) acc[i] = make_float2(0.f, 0.f);
  if (c > 0) {
    int j0 = cp[0];
    const unsigned int* p = slice + (size_t)j0*NSTRIDE;
    u32x4 q = *(const u32x4*)(p + lane*4);
    unsigned int te = p[256 + (lane >> 1)] >> sh;
    for (int k = 0; k < c; ++k) {
      float v = vp[k];
      int kn = (k + 1 < c) ? k + 1 : k;
      int jn = cp[kn];
      const unsigned int* pn = slice + (size_t)jn*NSTRIDE;
      u32x4 nq = *(const u32x4*)(pn + lane*4);
      unsigned int nte = pn[256 + (lane >> 1)] >> sh;
      fma4t(v, q, te, acc, acct);
      q = nq; te = nte;
    }
  }
  // x0 (plane 0), same lane mapping
  const unsigned int* xp = XAu + (size_t)cc*SLICE_DW + (size_t)n*NSTRIDE;
  u32x4 x0 = *(const u32x4*)(xp + lane*4);
  float xt = h16lo(xp[256 + (lane >> 1)] >> sh);
  unsigned int* dp = XAu + (size_t)cc*SLICE_DW + (size_t)n*NSTRIDE
                   + PLANE_OFF(2 + 2*s);
  float2 f;
  u32x4 w;
  f = u2f2(x0[0]); w[0] = packh(2.f*acc[0].x - f.x, 2.f*acc[0].y - f.y);
  f = u2f2(x0[1]); w[1] = packh(2.f*acc[1].x - f.x, 2.f*acc[1].y - f.y);
  f = u2f2(x0[2]); w[2] = packh(2.f*acc[2].x - f.x, 2.f*acc[2].y - f.y);
  f = u2f2(x0[3]); w[3] = packh(2.f*acc[3].x - f.x, 2.f*acc[3].y - f.y);
  __builtin_nontemporal_store(w, (u32x4*)(dp + lane*4));
  ((h16*)dp)[512 + lane] = __float2half_rn(2.f*acct - xt);
}

// ---------------- projection via MFMA, W in LDS, 2 nodes/block -------
// 512 threads = 8 waves. Waves 0-3 own node 2*blk, waves 4-7 own node
// 2*blk+1. Wave wq owns b-rows [16wq,16wq+16). A-fragments in regs
// across both stages. T14: stage-1 W prefetched to regs at kernel
// start (overlaps stage-0 fill + A-load latency); mid-kernel refill is
// pure ds_write (no global latency).
// mode 0: VAL[n][b][o] = sigmoid(acc+bias) fp16 (o in [0,128))
// mode 1: out = u*hx + (1-u)*tanh(acc+bias) fp32 (o in [0,64), 1 stage)
__global__ __launch_bounds__(512, 4) void k_projm(
    const unsigned int* __restrict__ XAu, const h16* __restrict__ Wz,
    const float* __restrict__ bias, h16* __restrict__ VAL,
    const float* __restrict__ hx, const h16* __restrict__ VALu,
    float* __restrict__ out, int mode)
{
  __shared__ h16 WL[4*12*64*8];            // 49,152 B
  const int t = threadIdx.x;
  const int w8 = t >> 6;                   // wave 0..7
  const int lane = t & 63;
  const int ni = w8 >> 2;                  // node slot 0/1
  const int wq = w8 & 3;                   // quad-wave within node
  const int quad = lane >> 4, lr = lane & 15;
  const int b0 = wq*16;
  const int cc = 2*wq + (lr >> 3), bs = lr & 7;
  const int n = blockIdx.x*2 + ni;

  // A fragments: read once, keep in registers across both stages.
  const h16* abase = (const h16*)(XAu + (size_t)cc*SLICE_DW + (size_t)n*NSTRIDE)
                   + bs*8 + quad*64;
  f16x8 a[12];
  #pragma unroll
  for (int k0 = 0; k0 < 12; ++k0) a[k0] = *(const f16x8*)(abase + k0*256);

  // T14: stage-1 W loads issued NOW (in flight with stage-0 fill).
  uint4 w1r[6];
  if (mode == 0) {
    const uint4* sg1 = (const uint4*)Wz + 3072;
    #pragma unroll
    for (int i = 0; i < 6; ++i) w1r[i] = sg1[t + i*512];
  }

  f32x4 acc[8];
  #pragma unroll
  for (int i = 0; i < 8; ++i) acc[i] = (f32x4){0.f,0.f,0.f,0.f};

  // ---- stage 0 (o in [0,64)) ----
  {
    uint4* dl = (uint4*)WL;
    const uint4* sg = (const uint4*)Wz;
    #pragma unroll
    for (int i = 0; i < 6; ++i) dl[t + i*512] = sg[t + i*512];
  }
  __syncthreads();
  #pragma unroll
  for (int k0 = 0; k0 < 12; ++k0) {
    #pragma unroll
    for (int ot = 0; ot < 4; ++ot) {
      f16x8 bf = *(const f16x8*)(WL + ((ot*12 + k0)*64 + lane)*8);
      acc[ot] = __builtin_amdgcn_mfma_f32_16x16x32_f16(a[k0], bf, acc[ot], 0, 0, 0);
    }
  }

  // ---- stage 1 (o in [64,128)), mode 0 only ----
  if (mode == 0) {
    __syncthreads();                       // stage-0 readers done
    {
      uint4* dl = (uint4*)WL;
      #pragma unroll
      for (int i = 0; i < 6; ++i) dl[t + i*512] = w1r[i];  // regs -> LDS
    }
    __syncthreads();
    #pragma unroll
    for (int k0 = 0; k0 < 12; ++k0) {
      #pragma unroll
      for (int ot = 0; ot < 4; ++ot) {
        f16x8 bf = *(const f16x8*)(WL + ((ot*12 + k0)*64 + lane)*8);
        acc[4+ot] = __builtin_amdgcn_mfma_f32_16x16x32_f16(a[k0], bf, acc[4+ot], 0, 0, 0);
      }
    }

    // epilogue mode 0: both stages
    #pragma unroll
    for (int st = 0; st < 2; ++st) {
      #pragma unroll
      for (int ot = 0; ot < 4; ++ot) {
        int o = st*64 + ot*16 + lr;
        float bia = bias[o];
        #pragma unroll
        for (int r = 0; r < 4; ++r) {
          int b = b0 + quad*4 + r;
          VAL[(size_t)n*8192 + b*128 + o] =
            __float2half_rn(fsigmoid(acc[st*4+ot][r] + bia));
        }
      }
    }
  } else {
    // epilogue mode 1
    #pragma unroll
    for (int ot = 0; ot < 4; ++ot) {
      int o = ot*16 + lr;
      float bia = bias[o];
      #pragma unroll
      for (int r = 0; r < 4; ++r) {
        int b = b0 + quad*4 + r;
        float cv = ftanh(acc[ot][r] + bia);
        float u  = __half2float(VALu[(size_t)n*8192 + b*128 + 64 + o]);
        float h  = hx[(size_t)b*(N_NODES*64) + n*64 + o];
        out[(size_t)b*(N_NODES*64) + n*64 + o] = u*h + (1.f - u)*cv;
      }
    }
  }
}

extern "C" void kernel_launch(void* const* d_in, const int* in_sizes, int n_in,
                              void* d_out, int out_size, void* d_ws, size_t ws_size,
                              hipStream_t stream)
{
  const float* inp      = (const float*)d_in[0];
  const float* hx       = (const float*)d_in[1];
  const float* supp     = (const float*)d_in[2];
  const float* mu_w_ru  = (const float*)d_in[3];
  const float* ls_w_ru  = (const float*)d_in[4];
  const float* mu_b_ru  = (const float*)d_in[5];
  const float* ls_b_ru  = (const float*)d_in[6];
  const float* eps_w_ru = (const float*)d_in[7];
  const float* eps_b_ru = (const float*)d_in[8];
  const float* mu_w_c   = (const float*)d_in[9];
  const float* ls_w_c   = (const float*)d_in[10];
  const float* mu_b_c   = (const float*)d_in[11];
  const float* ls_b_c   = (const float*)d_in[12];
  const float* eps_w_c  = (const float*)d_in[13];
  const float* eps_b_c  = (const float*)d_in[14];
  float* out = (float*)d_out;

  char* wsp = (char*)d_ws;
  size_t off = 0;
  auto take = [&](size_t bytes) -> void* {
    void* p = wsp + off;
    off = (off + bytes + 255) & ~(size_t)255;
    return p;
  };
  unsigned int* XAu = (unsigned int*)take(8*SLICE_DW*sizeof(unsigned int)); // 98.3 MB
  h16*   VAL = (h16*)  take((size_t)N_NODES*8192*sizeof(h16));       // 32.8 MB
  h16*   Wzru= (h16*)  take((size_t)8*12*64*8*sizeof(h16));          // 98.3 KB
  h16*   Wzc = (h16*)  take((size_t)4*12*64*8*sizeof(h16));          // 49.2 KB
  float* bru = (float*)take(128*sizeof(float));
  float* bc  = (float*)take(64*sizeof(float));
  int*   ellc= (int*)  take((size_t)2*N_NODES*ELLW*sizeof(int));     // 2.05 MB
  float* ellv= (float*)take((size_t)2*N_NODES*ELLW*sizeof(float));   // 2.05 MB
  int*   cnt = (int*)  take((size_t)2*N_NODES*sizeof(int));
  // total ~135.3 MB
  (void)ws_size;

  hipMemsetAsync(cnt, 0, (size_t)2*N_NODES*sizeof(int), stream);
  k_weights<<<289, 256, 0, stream>>>(mu_w_ru, ls_w_ru, eps_w_ru,
                                     mu_b_ru, ls_b_ru, eps_b_ru,
                                     mu_w_c, ls_w_c, eps_w_c,
                                     mu_b_c, ls_b_c, eps_b_c,
                                     Wzru, bru, Wzc, bc);
  k_ell<<<dim3(8, N_NODES, 2), 256, 0, stream>>>(supp, ellc, ellv, cnt);

  for (int pass = 0; pass < 2; ++pass) {
    k_build0<<<N_NODES, 256, 0, stream>>>(inp, hx, VAL, XAu, pass);
    k_spmm <<<dim3(8, 1000), 256, 0, stream>>>(XAu, ellc, ellv, cnt);
    k_cheb <<<dim3(8, 1000), 256, 0, stream>>>(XAu, ellc, ellv, cnt);
    if (pass == 0)
      k_projm<<<N_NODES/2, 512, 0, stream>>>(XAu, Wzru, bru, VAL,
                                             nullptr, nullptr, nullptr, 0);
    else
      k_projm<<<N_NODES/2, 512, 0, stream>>>(XAu, Wzc, bc, nullptr,
                                             hx, VAL, out, 1);
  }
}

// Round 7
// 509.265 us; speedup vs baseline: 1.0401x; 1.0401x over previous
//
#include <hip/hip_runtime.h>
#include <hip/hip_fp16.h>

// RandDCGRUCell on MI355X.
// B=64, N=2000, IN_DIM=2, U=64, D=66, NSUP=2, K=2, M=5.
// R18: revert R17's k_projm reg-prefetch (cost ~26us: +24 VGPR under
// the 128-cap -> spill/serialization; T14 prereq "VGPR headroom" absent).
// Back to R15 exactly = best known (504us, tied with R13's 503).
// Gather verdict: R13/R15/R16 (3 different structures) all 65-68us =>
// L2 line-delivery floor (~1.1GB/dispatch from L2 @ ~16.5 TB/s agg);
// do not tune further.
// R15: one row per wave64, scalarized ELL walk (s_load cols/vals).
// R13: k_projm 512-thr node-parallel, A-frags in regs across stages.

#define N_NODES 2000
#define BATCH   64
#define MMATS   5
#define ELLW    128
#define NSTRIDE 1536            // dwords per (cc, n): 48 kb * 32
#define SLICE_DW ((size_t)N_NODES * NSTRIDE)   // dwords per chunk (3,072,000)
#define PLANE_OFF(p) ((p)*288)  // dword offset of plane p within (cc,n)

typedef __half h16;
typedef _Float16 f16x8 __attribute__((ext_vector_type(8)));
typedef float    f32x4 __attribute__((ext_vector_type(4)));
typedef unsigned int u32x4 __attribute__((ext_vector_type(4)));

__device__ __forceinline__ __half2 f2h2(float a, float b) {
  __half2 r; r.x = __float2half_rn(a); r.y = __float2half_rn(b); return r;
}
__device__ __forceinline__ unsigned int packh(float a, float b) {
  __half2 h = f2h2(a, b);
  return __builtin_bit_cast(unsigned int, h);
}
__device__ __forceinline__ float2 u2f2(unsigned int u) {
  return __half22float2(__builtin_bit_cast(__half2, u));
}
__device__ __forceinline__ float h16lo(unsigned int u) {
  __half h = __builtin_bit_cast(__half2, u).x;
  return __half2float(h);
}
__device__ __forceinline__ float fexp2(float x) {
#if __has_builtin(__builtin_amdgcn_exp2f)
  return __builtin_amdgcn_exp2f(x);
#else
  return exp2f(x);
#endif
}
__device__ __forceinline__ float frcp(float x) {
#if __has_builtin(__builtin_amdgcn_rcpf)
  return __builtin_amdgcn_rcpf(x);
#else
  return 1.f/x;
#endif
}
#define LOG2E 1.44269504088896f
__device__ __forceinline__ float fsigmoid(float x) {
  return frcp(1.f + fexp2(-LOG2E*x));
}
__device__ __forceinline__ float ftanh(float x) {
  return 1.f - 2.f*frcp(1.f + fexp2((2.f*LOG2E)*x));
}

// 4-dword + tail-half elementwise FMA: acc[i] += v * half2(dword_i)
__device__ __forceinline__ void fma4t(float v, u32x4 q, unsigned int te,
                                      float2* acc, float& acct) {
  float2 f;
  f = u2f2(q[0]); acc[0].x = fmaf(v,f.x,acc[0].x); acc[0].y = fmaf(v,f.y,acc[0].y);
  f = u2f2(q[1]); acc[1].x = fmaf(v,f.x,acc[1].x); acc[1].y = fmaf(v,f.y,acc[1].y);
  f = u2f2(q[2]); acc[2].x = fmaf(v,f.x,acc[2].x); acc[2].y = fmaf(v,f.y,acc[2].y);
  f = u2f2(q[3]); acc[3].x = fmaf(v,f.x,acc[3].x); acc[3].y = fmaf(v,f.y,acc[3].y);
  acct = fmaf(v, h16lo(te), acct);
}

// ---------------- weights: fragment-order swizzled fp16 W -----------
// Wz[((ot*12 + k0)*64 + lane)*8 + j] = W[k][o], k = k0*32 + (lane>>4)*8 + j,
// o = ot*16 + (lane&15); k = 72p + d (plane-major), d<66 valid, k>=360 -> 0.
__global__ __launch_bounds__(256) void k_weights(
    const float* __restrict__ mu_w_ru, const float* __restrict__ ls_w_ru, const float* __restrict__ eps_w_ru,
    const float* __restrict__ mu_b_ru, const float* __restrict__ ls_b_ru, const float* __restrict__ eps_b_ru,
    const float* __restrict__ mu_w_c,  const float* __restrict__ ls_w_c,  const float* __restrict__ eps_w_c,
    const float* __restrict__ mu_b_c,  const float* __restrict__ ls_b_c,  const float* __restrict__ eps_b_c,
    h16* __restrict__ Wzru, float* __restrict__ bru,
    h16* __restrict__ Wzc,  float* __restrict__ bc)
{
  int idx = blockIdx.x*256 + threadIdx.x;
  const int n_ru = 8*12*64*8;   // 49152
  const int n_c  = 4*12*64*8;   // 24576
  if (idx < n_ru) {
    int j = idx & 7, ln = (idx >> 3) & 63, rest = idx >> 9;
    int k = (rest % 12)*32 + (ln >> 4)*8 + j;
    int o = (rest / 12)*16 + (ln & 15);
    float wv = 0.f;
    if (k < 360) {
      int p = k/72, d = k - p*72;
      if (d < 66) {
        int r = (d*MMATS + p)*128 + o;
        wv = mu_w_ru[r] + expf(ls_w_ru[r]) * eps_w_ru[r];
      }
    }
    Wzru[idx] = __float2half_rn(wv);
  } else if (idx < n_ru + n_c) {
    int i = idx - n_ru;
    int j = i & 7, ln = (i >> 3) & 63, rest = i >> 9;
    int k = (rest % 12)*32 + (ln >> 4)*8 + j;
    int o = (rest / 12)*16 + (ln & 15);
    float wv = 0.f;
    if (k < 360) {
      int p = k/72, d = k - p*72;
      if (d < 66) {
        int r = (d*MMATS + p)*64 + o;
        wv = mu_w_c[r] + expf(ls_w_c[r]) * eps_w_c[r];
      }
    }
    Wzc[i] = __float2half_rn(wv);
  } else if (idx < n_ru + n_c + 128) {
    int i = idx - n_ru - n_c;
    bru[i] = mu_b_ru[i] + expf(ls_b_ru[i]) * eps_b_ru[i];
  } else if (idx < n_ru + n_c + 128 + 64) {
    int i = idx - n_ru - n_c - 128;
    bc[i] = mu_b_c[i] + expf(ls_b_c[i]) * eps_b_c[i];
  }
}

// ---------------- ELL build (order within row irrelevant for a sum) --
__global__ __launch_bounds__(256) void k_ell(
    const float* __restrict__ supp, int* __restrict__ cols,
    float* __restrict__ vals, int* __restrict__ cnt)
{
  int j = blockIdx.x*256 + threadIdx.x;
  if (j >= N_NODES) return;
  int n = blockIdx.y, s = blockIdx.z;
  int r = s*N_NODES + n;
  float v = supp[(size_t)r*N_NODES + j];
  if (v != 0.f) {
    int p = atomicAdd(cnt + r, 1);
    if (p < ELLW) {
      cols[(size_t)r*ELLW + p] = j;
      vals[(size_t)r*ELLW + p] = v;
    }
  }
}

// ---------------- build x0 plane (p=0) + zero pad blocks -------------
// XA micro-block layout per (cc,n): [48kb][8bs][8k] halfs (1536 dwords).
__global__ __launch_bounds__(256) void k_build0(
    const float* __restrict__ inp, const float* __restrict__ hx,
    const h16* __restrict__ VALr, unsigned int* __restrict__ XAu, int mode)
{
  const int n = blockIdx.x;
  const int g = threadIdx.x >> 5, tt = threadIdx.x & 31;
  const int b = g*8 + (tt >> 2);
  unsigned int* dst = XAu + (size_t)g*SLICE_DW + (size_t)n*NSTRIDE;
  #pragma unroll
  for (int kb = 0; kb < 9; ++kb) {
    int d0 = kb*8 + 2*(tt & 3);
    float v[2];
    #pragma unroll
    for (int q = 0; q < 2; ++q) {
      int d = d0 + q;
      float x = 0.f;
      if (d < 2) {
        x = inp[(size_t)b*(N_NODES*2) + n*2 + d];
      } else if (d < 66) {
        x = hx[(size_t)b*(N_NODES*64) + n*64 + (d-2)];
        if (mode == 1) x *= __half2float(VALr[(size_t)n*8192 + b*128 + (d-2)]);
      }
      v[q] = x;
    }
    dst[kb*32 + tt] = packh(v[0], v[1]);
  }
  dst[45*32 + tt] = 0u;  // pad kbs 45..47 (k in [360,384))
  dst[46*32 + tt] = 0u;
  dst[47*32 + tt] = 0u;
}

// ---------------- SpMM: plane(1+2s) = S_s @ plane0 -------------------
// One row per wave64. Scalar (SGPR) ELL walk; lane owns dwords
// [4L,4L+4) + half of dword 256+(L>>1). 2-deep VMEM prefetch.
__global__ __launch_bounds__(256) void k_spmm(
    unsigned int* __restrict__ XAu, const int* __restrict__ cols,
    const float* __restrict__ vals, const int* __restrict__ cnt)
{
  const int cc = blockIdx.x;
  const int lane = threadIdx.x & 63;
  const int rr = blockIdx.y*4 + (threadIdx.x >> 6);
  const int r  = __builtin_amdgcn_readfirstlane(rr);
  const int s  = (r >= N_NODES) ? 1 : 0;
  const int n  = r - s*N_NODES;
  int c = cnt[r]; if (c > ELLW) c = ELLW;
  const int*   cp = cols + (size_t)r*ELLW;
  const float* vp = vals + (size_t)r*ELLW;
  const unsigned int* slice = XAu + (size_t)cc*SLICE_DW;   // plane 0 offset 0
  const int sh = (lane & 1) * 16;          // tail half select
  float2 acc[4];
  float  acct = 0.f;
  #pragma unroll
  for (int i = 0; i < 4; ++i) acc[i] = make_float2(0.f, 0.f);
  if (c > 0) {
    int j0 = cp[0];
    const unsigned int* p = slice + (size_t)j0*NSTRIDE;
    u32x4 q = *(const u32x4*)(p + lane*4);
    unsigned int te = p[256 + (lane >> 1)] >> sh;
    for (int k = 0; k < c; ++k) {
      float v = vp[k];
      int kn = (k + 1 < c) ? k + 1 : k;
      int jn = cp[kn];
      const unsigned int* pn = slice + (size_t)jn*NSTRIDE;
      u32x4 nq = *(const u32x4*)(pn + lane*4);
      unsigned int nte = pn[256 + (lane >> 1)] >> sh;
      fma4t(v, q, te, acc, acct);
      q = nq; te = nte;
    }
  }
  unsigned int* dp = XAu + (size_t)cc*SLICE_DW + (size_t)n*NSTRIDE
                   + PLANE_OFF(1 + 2*s);
  u32x4 w;
  w[0] = packh(acc[0].x,acc[0].y); w[1] = packh(acc[1].x,acc[1].y);
  w[2] = packh(acc[2].x,acc[2].y); w[3] = packh(acc[3].x,acc[3].y);
  *(u32x4*)(dp + lane*4) = w;
  ((h16*)dp)[512 + lane] = __float2half_rn(acct);
}

// ---------------- Chebyshev: plane(2+2s) = 2*S_s@plane(1+2s) - plane0 -
__global__ __launch_bounds__(256) void k_cheb(
    unsigned int* __restrict__ XAu, const int* __restrict__ cols,
    const float* __restrict__ vals, const int* __restrict__ cnt)
{
  const int cc = blockIdx.x;
  const int lane = threadIdx.x & 63;
  const int rr = blockIdx.y*4 + (threadIdx.x >> 6);
  const int r  = __builtin_amdgcn_readfirstlane(rr);
  const int s  = (r >= N_NODES) ? 1 : 0;
  const int n  = r - s*N_NODES;
  int c = cnt[r]; if (c > ELLW) c = ELLW;
  const int*   cp = cols + (size_t)r*ELLW;
  const float* vp = vals + (size_t)r*ELLW;
  const unsigned int* slice = XAu + (size_t)cc*SLICE_DW + PLANE_OFF(1 + 2*s);
  const int sh = (lane & 1) * 16;
  float2 acc[4];
  float  acct = 0.f;
  #pragma unroll
  for (int i = 0; i < 4; ++i) acc[i] = make_float2(0.f, 0.f);
  if (c > 0) {
    int j0 = cp[0];
    const unsigned int* p = slice + (size_t)j0*NSTRIDE;
    u32x4 q = *(const u32x4*)(p + lane*4);
    unsigned int te = p[256 + (lane >> 1)] >> sh;
    for (int k = 0; k < c; ++k) {
      float v = vp[k];
      int kn = (k + 1 < c) ? k + 1 : k;
      int jn = cp[kn];
      const unsigned int* pn = slice + (size_t)jn*NSTRIDE;
      u32x4 nq = *(const u32x4*)(pn + lane*4);
      unsigned int nte = pn[256 + (lane >> 1)] >> sh;
      fma4t(v, q, te, acc, acct);
      q = nq; te = nte;
    }
  }
  // x0 (plane 0), same lane mapping
  const unsigned int* xp = XAu + (size_t)cc*SLICE_DW + (size_t)n*NSTRIDE;
  u32x4 x0 = *(const u32x4*)(xp + lane*4);
  float xt = h16lo(xp[256 + (lane >> 1)] >> sh);
  unsigned int* dp = XAu + (size_t)cc*SLICE_DW + (size_t)n*NSTRIDE
                   + PLANE_OFF(2 + 2*s);
  float2 f;
  u32x4 w;
  f = u2f2(x0[0]); w[0] = packh(2.f*acc[0].x - f.x, 2.f*acc[0].y - f.y);
  f = u2f2(x0[1]); w[1] = packh(2.f*acc[1].x - f.x, 2.f*acc[1].y - f.y);
  f = u2f2(x0[2]); w[2] = packh(2.f*acc[2].x - f.x, 2.f*acc[2].y - f.y);
  f = u2f2(x0[3]); w[3] = packh(2.f*acc[3].x - f.x, 2.f*acc[3].y - f.y);
  __builtin_nontemporal_store(w, (u32x4*)(dp + lane*4));
  ((h16*)dp)[512 + lane] = __float2half_rn(2.f*acct - xt);
}

// ---------------- projection via MFMA, W in LDS, 2 nodes/block -------
// 512 threads = 8 waves. Waves 0-3 own node 2*blk, waves 4-7 own node
// 2*blk+1 (concurrent, not serial). Wave wq owns b-rows [16wq,16wq+16).
// A-fragments (12 x f16x8 = 48 VGPR) loaded ONCE and held across both
// o-half stages; acc[0..7] statically indexed (stages unrolled).
// R18: NO stage-1 reg-prefetch (R17 showed it spills under the 128-VGPR
// cap and costs ~13us/dispatch).
// mode 0: VAL[n][b][o] = sigmoid(acc+bias) fp16 (o in [0,128))
// mode 1: out = u*hx + (1-u)*tanh(acc+bias) fp32 (o in [0,64), 1 stage)
__global__ __launch_bounds__(512, 4) void k_projm(
    const unsigned int* __restrict__ XAu, const h16* __restrict__ Wz,
    const float* __restrict__ bias, h16* __restrict__ VAL,
    const float* __restrict__ hx, const h16* __restrict__ VALu,
    float* __restrict__ out, int mode)
{
  __shared__ h16 WL[4*12*64*8];            // 49,152 B
  const int t = threadIdx.x;
  const int w8 = t >> 6;                   // wave 0..7
  const int lane = t & 63;
  const int ni = w8 >> 2;                  // node slot 0/1
  const int wq = w8 & 3;                   // quad-wave within node
  const int quad = lane >> 4, lr = lane & 15;
  const int b0 = wq*16;
  const int cc = 2*wq + (lr >> 3), bs = lr & 7;
  const int n = blockIdx.x*2 + ni;

  // A fragments: read once, keep in registers across both stages.
  const h16* abase = (const h16*)(XAu + (size_t)cc*SLICE_DW + (size_t)n*NSTRIDE)
                   + bs*8 + quad*64;
  f16x8 a[12];
  #pragma unroll
  for (int k0 = 0; k0 < 12; ++k0) a[k0] = *(const f16x8*)(abase + k0*256);

  f32x4 acc[8];
  #pragma unroll
  for (int i = 0; i < 8; ++i) acc[i] = (f32x4){0.f,0.f,0.f,0.f};

  // ---- stage 0 (o in [0,64)) ----
  {
    uint4* dl = (uint4*)WL;
    const uint4* sg = (const uint4*)Wz;
    #pragma unroll
    for (int i = 0; i < 6; ++i) dl[t + i*512] = sg[t + i*512];
  }
  __syncthreads();
  #pragma unroll
  for (int k0 = 0; k0 < 12; ++k0) {
    #pragma unroll
    for (int ot = 0; ot < 4; ++ot) {
      f16x8 bf = *(const f16x8*)(WL + ((ot*12 + k0)*64 + lane)*8);
      acc[ot] = __builtin_amdgcn_mfma_f32_16x16x32_f16(a[k0], bf, acc[ot], 0, 0, 0);
    }
  }

  // ---- stage 1 (o in [64,128)), mode 0 only ----
  if (mode == 0) {
    __syncthreads();                       // stage-0 readers done
    {
      uint4* dl = (uint4*)WL;
      const uint4* sg = (const uint4*)Wz + 3072;
      #pragma unroll
      for (int i = 0; i < 6; ++i) dl[t + i*512] = sg[t + i*512];
    }
    __syncthreads();
    #pragma unroll
    for (int k0 = 0; k0 < 12; ++k0) {
      #pragma unroll
      for (int ot = 0; ot < 4; ++ot) {
        f16x8 bf = *(const f16x8*)(WL + ((ot*12 + k0)*64 + lane)*8);
        acc[4+ot] = __builtin_amdgcn_mfma_f32_16x16x32_f16(a[k0], bf, acc[4+ot], 0, 0, 0);
      }
    }

    // epilogue mode 0: both stages
    #pragma unroll
    for (int st = 0; st < 2; ++st) {
      #pragma unroll
      for (int ot = 0; ot < 4; ++ot) {
        int o = st*64 + ot*16 + lr;
        float bia = bias[o];
        #pragma unroll
        for (int r = 0; r < 4; ++r) {
          int b = b0 + quad*4 + r;
          VAL[(size_t)n*8192 + b*128 + o] =
            __float2half_rn(fsigmoid(acc[st*4+ot][r] + bia));
        }
      }
    }
  } else {
    // epilogue mode 1
    #pragma unroll
    for (int ot = 0; ot < 4; ++ot) {
      int o = ot*16 + lr;
      float bia = bias[o];
      #pragma unroll
      for (int r = 0; r < 4; ++r) {
        int b = b0 + quad*4 + r;
        float cv = ftanh(acc[ot][r] + bia);
        float u  = __half2float(VALu[(size_t)n*8192 + b*128 + 64 + o]);
        float h  = hx[(size_t)b*(N_NODES*64) + n*64 + o];
        out[(size_t)b*(N_NODES*64) + n*64 + o] = u*h + (1.f - u)*cv;
      }
    }
  }
}

extern "C" void kernel_launch(void* const* d_in, const int* in_sizes, int n_in,
                              void* d_out, int out_size, void* d_ws, size_t ws_size,
                              hipStream_t stream)
{
  const float* inp      = (const float*)d_in[0];
  const float* hx       = (const float*)d_in[1];
  const float* supp     = (const float*)d_in[2];
  const float* mu_w_ru  = (const float*)d_in[3];
  const float* ls_w_ru  = (const float*)d_in[4];
  const float* mu_b_ru  = (const float*)d_in[5];
  const float* ls_b_ru  = (const float*)d_in[6];
  const float* eps_w_ru = (const float*)d_in[7];
  const float* eps_b_ru = (const float*)d_in[8];
  const float* mu_w_c   = (const float*)d_in[9];
  const float* ls_w_c   = (const float*)d_in[10];
  const float* mu_b_c   = (const float*)d_in[11];
  const float* ls_b_c   = (const float*)d_in[12];
  const float* eps_w_c  = (const float*)d_in[13];
  const float* eps_b_c  = (const float*)d_in[14];
  float* out = (float*)d_out;

  char* wsp = (char*)d_ws;
  size_t off = 0;
  auto take = [&](size_t bytes) -> void* {
    void* p = wsp + off;
    off = (off + bytes + 255) & ~(size_t)255;
    return p;
  };
  unsigned int* XAu = (unsigned int*)take(8*SLICE_DW*sizeof(unsigned int)); // 98.3 MB
  h16*   VAL = (h16*)  take((size_t)N_NODES*8192*sizeof(h16));       // 32.8 MB
  h16*   Wzru= (h16*)  take((size_t)8*12*64*8*sizeof(h16));          // 98.3 KB
  h16*   Wzc = (h16*)  take((size_t)4*12*64*8*sizeof(h16));          // 49.2 KB
  float* bru = (float*)take(128*sizeof(float));
  float* bc  = (float*)take(64*sizeof(float));
  int*   ellc= (int*)  take((size_t)2*N_NODES*ELLW*sizeof(int));     // 2.05 MB
  float* ellv= (float*)take((size_t)2*N_NODES*ELLW*sizeof(float));   // 2.05 MB
  int*   cnt = (int*)  take((size_t)2*N_NODES*sizeof(int));
  // total ~135.3 MB
  (void)ws_size;

  hipMemsetAsync(cnt, 0, (size_t)2*N_NODES*sizeof(int), stream);
  k_weights<<<289, 256, 0, stream>>>(mu_w_ru, ls_w_ru, eps_w_ru,
                                     mu_b_ru, ls_b_ru, eps_b_ru,
                                     mu_w_c, ls_w_c, eps_w_c,
                                     mu_b_c, ls_b_c, eps_b_c,
                                     Wzru, bru, Wzc, bc);
  k_ell<<<dim3(8, N_NODES, 2), 256, 0, stream>>>(supp, ellc, ellv, cnt);

  for (int pass = 0; pass < 2; ++pass) {
    k_build0<<<N_NODES, 256, 0, stream>>>(inp, hx, VAL, XAu, pass);
    k_spmm <<<dim3(8, 1000), 256, 0, stream>>>(XAu, ellc, ellv, cnt);
    k_cheb <<<dim3(8, 1000), 256, 0, stream>>>(XAu, ellc, ellv, cnt);
    if (pass == 0)
      k_projm<<<N_NODES/2, 512, 0, stream>>>(XAu, Wzru, bru, VAL,
                                             nullptr, nullptr, nullptr, 0);
    else
      k_projm<<<N_NODES/2, 512, 0, stream>>>(XAu, Wzc, bc, nullptr,
                                             hx, VAL, out, 1);
  }
}

// Round 8
// 468.722 us; speedup vs baseline: 1.1300x; 1.0865x over previous
//
#include <hip/hip_runtime.h>
#include <hip/hip_fp16.h>

// RandDCGRUCell on MI355X.
// B=64, N=2000, IN_DIM=2, U=64, D=66, NSUP=2, K=2, M=5.
// R19: k_build0 was line-inefficient + latency-bound (18 scalar strided
// hx loads/thread, 32B-useful per 64B line). Rewritten: coalesced float4
// loads -> LDS transpose T[d][b] -> pure-bit-pack dword stores. Mode-1
// input premultiplied: projm mode-0 epilogue now writes RHX = sig(r)*hx
// (fp16, compact [n][b][64]) and VALU = sig(u) ([n][b][64]) instead of
// interleaved VAL[n][b][128]; build0 pass-1 streams RHX coalesced.
// Gather verdict (R13/R15/R16): 65-68us invariant across 3 structures =>
// TCP line-delivery floor; do not tune further.
// R15: one row per wave64, scalarized ELL walk. R13: projm node-parallel.

#define N_NODES 2000
#define BATCH   64
#define MMATS   5
#define ELLW    128
#define NSTRIDE 1536            // dwords per (cc, n): 48 kb * 32
#define SLICE_DW ((size_t)N_NODES * NSTRIDE)   // dwords per chunk (3,072,000)
#define PLANE_OFF(p) ((p)*288)  // dword offset of plane p within (cc,n)

typedef __half h16;
typedef _Float16 f16x8 __attribute__((ext_vector_type(8)));
typedef float    f32x4 __attribute__((ext_vector_type(4)));
typedef unsigned int u32x4 __attribute__((ext_vector_type(4)));

__device__ __forceinline__ __half2 f2h2(float a, float b) {
  __half2 r; r.x = __float2half_rn(a); r.y = __float2half_rn(b); return r;
}
__device__ __forceinline__ unsigned int packh(float a, float b) {
  __half2 h = f2h2(a, b);
  return __builtin_bit_cast(unsigned int, h);
}
__device__ __forceinline__ float2 u2f2(unsigned int u) {
  return __half22float2(__builtin_bit_cast(__half2, u));
}
__device__ __forceinline__ float h16lo(unsigned int u) {
  __half h = __builtin_bit_cast(__half2, u).x;
  return __half2float(h);
}
__device__ __forceinline__ unsigned short hbits(float x) {
  return __builtin_bit_cast(unsigned short, __float2half_rn(x));
}
__device__ __forceinline__ float fexp2(float x) {
#if __has_builtin(__builtin_amdgcn_exp2f)
  return __builtin_amdgcn_exp2f(x);
#else
  return exp2f(x);
#endif
}
__device__ __forceinline__ float frcp(float x) {
#if __has_builtin(__builtin_amdgcn_rcpf)
  return __builtin_amdgcn_rcpf(x);
#else
  return 1.f/x;
#endif
}
#define LOG2E 1.44269504088896f
__device__ __forceinline__ float fsigmoid(float x) {
  return frcp(1.f + fexp2(-LOG2E*x));
}
__device__ __forceinline__ float ftanh(float x) {
  return 1.f - 2.f*frcp(1.f + fexp2((2.f*LOG2E)*x));
}

// 4-dword + tail-half elementwise FMA: acc[i] += v * half2(dword_i)
__device__ __forceinline__ void fma4t(float v, u32x4 q, unsigned int te,
                                      float2* acc, float& acct) {
  float2 f;
  f = u2f2(q[0]); acc[0].x = fmaf(v,f.x,acc[0].x); acc[0].y = fmaf(v,f.y,acc[0].y);
  f = u2f2(q[1]); acc[1].x = fmaf(v,f.x,acc[1].x); acc[1].y = fmaf(v,f.y,acc[1].y);
  f = u2f2(q[2]); acc[2].x = fmaf(v,f.x,acc[2].x); acc[2].y = fmaf(v,f.y,acc[2].y);
  f = u2f2(q[3]); acc[3].x = fmaf(v,f.x,acc[3].x); acc[3].y = fmaf(v,f.y,acc[3].y);
  acct = fmaf(v, h16lo(te), acct);
}

// ---------------- weights: fragment-order swizzled fp16 W -----------
// Wz[((ot*12 + k0)*64 + lane)*8 + j] = W[k][o], k = k0*32 + (lane>>4)*8 + j,
// o = ot*16 + (lane&15); k = 72p + d (plane-major), d<66 valid, k>=360 -> 0.
__global__ __launch_bounds__(256) void k_weights(
    const float* __restrict__ mu_w_ru, const float* __restrict__ ls_w_ru, const float* __restrict__ eps_w_ru,
    const float* __restrict__ mu_b_ru, const float* __restrict__ ls_b_ru, const float* __restrict__ eps_b_ru,
    const float* __restrict__ mu_w_c,  const float* __restrict__ ls_w_c,  const float* __restrict__ eps_w_c,
    const float* __restrict__ mu_b_c,  const float* __restrict__ ls_b_c,  const float* __restrict__ eps_b_c,
    h16* __restrict__ Wzru, float* __restrict__ bru,
    h16* __restrict__ Wzc,  float* __restrict__ bc)
{
  int idx = blockIdx.x*256 + threadIdx.x;
  const int n_ru = 8*12*64*8;   // 49152
  const int n_c  = 4*12*64*8;   // 24576
  if (idx < n_ru) {
    int j = idx & 7, ln = (idx >> 3) & 63, rest = idx >> 9;
    int k = (rest % 12)*32 + (ln >> 4)*8 + j;
    int o = (rest / 12)*16 + (ln & 15);
    float wv = 0.f;
    if (k < 360) {
      int p = k/72, d = k - p*72;
      if (d < 66) {
        int r = (d*MMATS + p)*128 + o;
        wv = mu_w_ru[r] + expf(ls_w_ru[r]) * eps_w_ru[r];
      }
    }
    Wzru[idx] = __float2half_rn(wv);
  } else if (idx < n_ru + n_c) {
    int i = idx - n_ru;
    int j = i & 7, ln = (i >> 3) & 63, rest = i >> 9;
    int k = (rest % 12)*32 + (ln >> 4)*8 + j;
    int o = (rest / 12)*16 + (ln & 15);
    float wv = 0.f;
    if (k < 360) {
      int p = k/72, d = k - p*72;
      if (d < 66) {
        int r = (d*MMATS + p)*64 + o;
        wv = mu_w_c[r] + expf(ls_w_c[r]) * eps_w_c[r];
      }
    }
    Wzc[i] = __float2half_rn(wv);
  } else if (idx < n_ru + n_c + 128) {
    int i = idx - n_ru - n_c;
    bru[i] = mu_b_ru[i] + expf(ls_b_ru[i]) * eps_b_ru[i];
  } else if (idx < n_ru + n_c + 128 + 64) {
    int i = idx - n_ru - n_c - 128;
    bc[i] = mu_b_c[i] + expf(ls_b_c[i]) * eps_b_c[i];
  }
}

// ---------------- ELL build (order within row irrelevant for a sum) --
__global__ __launch_bounds__(256) void k_ell(
    const float* __restrict__ supp, int* __restrict__ cols,
    float* __restrict__ vals, int* __restrict__ cnt)
{
  int j = blockIdx.x*256 + threadIdx.x;
  if (j >= N_NODES) return;
  int n = blockIdx.y, s = blockIdx.z;
  int r = s*N_NODES + n;
  float v = supp[(size_t)r*N_NODES + j];
  if (v != 0.f) {
    int p = atomicAdd(cnt + r, 1);
    if (p < ELLW) {
      cols[(size_t)r*ELLW + p] = j;
      vals[(size_t)r*ELLW + p] = v;
    }
  }
}

// ---------------- build x0 plane (p=0) + zero pad blocks -------------
// XA micro-block layout per (cc,n): [48kb][8bs][8k] halfs (1536 dwords).
// R19: phase 1 = coalesced loads -> LDS transpose T[d][b]; phase 2 =
// bit-pack dword stores (no float math). mode 1 reads premultiplied RHX.
__global__ __launch_bounds__(256) void k_build0(
    const float* __restrict__ inp, const float* __restrict__ hx,
    const h16* __restrict__ rhx, unsigned int* __restrict__ XAu, int mode)
{
  __shared__ unsigned short T[66][66];     // [d][b], +2 pad halfs/row
  const int n = blockIdx.x;
  const int t = threadIdx.x;
  if (mode == 0) {
    #pragma unroll
    for (int it = 0; it < 4; ++it) {
      int flat = it*256 + t;               // 1024 float4 chunks: 64 b x 16
      int b = flat >> 4, q = flat & 15;
      float4 v = *(const float4*)(hx + (size_t)b*(N_NODES*64) + n*64 + q*4);
      T[2 + q*4 + 0][b] = hbits(v.x);
      T[2 + q*4 + 1][b] = hbits(v.y);
      T[2 + q*4 + 2][b] = hbits(v.z);
      T[2 + q*4 + 3][b] = hbits(v.w);
    }
  } else {
    const unsigned short* rs = (const unsigned short*)rhx;
    #pragma unroll
    for (int it = 0; it < 2; ++it) {
      int flat = it*256 + t;               // 512 chunks of 8 halfs: 64 b x 8
      int b = flat >> 3, q = flat & 7;
      u32x4 v = *(const u32x4*)(rs + (size_t)n*4096 + b*64 + q*8);
      #pragma unroll
      for (int i = 0; i < 4; ++i) {
        T[2 + q*8 + 2*i + 0][b] = (unsigned short)(v[i] & 0xffffu);
        T[2 + q*8 + 2*i + 1][b] = (unsigned short)(v[i] >> 16);
      }
    }
  }
  if (t < 128) {
    int b = t >> 1, j = t & 1;
    T[j][b] = hbits(inp[(size_t)b*(N_NODES*2) + n*2 + j]);
  }
  __syncthreads();
  const int g = t >> 5, tt = t & 31;
  const int b = g*8 + (tt >> 2);
  const int dp = tt & 3;
  unsigned int* dst = XAu + (size_t)g*SLICE_DW + (size_t)n*NSTRIDE;
  #pragma unroll
  for (int kb = 0; kb < 9; ++kb) {
    int d0 = kb*8 + 2*dp;
    unsigned int lo = (d0     < 66) ? (unsigned int)T[d0][b]     : 0u;
    unsigned int hi = (d0 + 1 < 66) ? (unsigned int)T[d0 + 1][b] : 0u;
    dst[kb*32 + tt] = lo | (hi << 16);
  }
  dst[45*32 + tt] = 0u;  // pad kbs 45..47 (k in [360,384))
  dst[46*32 + tt] = 0u;
  dst[47*32 + tt] = 0u;
}

// ---------------- SpMM: plane(1+2s) = S_s @ plane0 -------------------
// One row per wave64. Scalar (SGPR) ELL walk; lane owns dwords
// [4L,4L+4) + half of dword 256+(L>>1). 2-deep VMEM prefetch.
__global__ __launch_bounds__(256) void k_spmm(
    unsigned int* __restrict__ XAu, const int* __restrict__ cols,
    const float* __restrict__ vals, const int* __restrict__ cnt)
{
  const int cc = blockIdx.x;
  const int lane = threadIdx.x & 63;
  const int rr = blockIdx.y*4 + (threadIdx.x >> 6);
  const int r  = __builtin_amdgcn_readfirstlane(rr);
  const int s  = (r >= N_NODES) ? 1 : 0;
  const int n  = r - s*N_NODES;
  int c = cnt[r]; if (c > ELLW) c = ELLW;
  const int*   cp = cols + (size_t)r*ELLW;
  const float* vp = vals + (size_t)r*ELLW;
  const unsigned int* slice = XAu + (size_t)cc*SLICE_DW;   // plane 0 offset 0
  const int sh = (lane & 1) * 16;          // tail half select
  float2 acc[4];
  float  acct = 0.f;
  #pragma unroll
  for (int i = 0; i < 4; ++i) acc[i] = make_float2(0.f, 0.f);
  if (c > 0) {
    int j0 = cp[0];
    const unsigned int* p = slice + (size_t)j0*NSTRIDE;
    u32x4 q = *(const u32x4*)(p + lane*4);
    unsigned int te = p[256 + (lane >> 1)] >> sh;
    for (int k = 0; k < c; ++k) {
      float v = vp[k];
      int kn = (k + 1 < c) ? k + 1 : k;
      int jn = cp[kn];
      const unsigned int* pn = slice + (size_t)jn*NSTRIDE;
      u32x4 nq = *(const u32x4*)(pn + lane*4);
      unsigned int nte = pn[256 + (lane >> 1)] >> sh;
      fma4t(v, q, te, acc, acct);
      q = nq; te = nte;
    }
  }
  unsigned int* dp = XAu + (size_t)cc*SLICE_DW + (size_t)n*NSTRIDE
                   + PLANE_OFF(1 + 2*s);
  u32x4 w;
  w[0] = packh(acc[0].x,acc[0].y); w[1] = packh(acc[1].x,acc[1].y);
  w[2] = packh(acc[2].x,acc[2].y); w[3] = packh(acc[3].x,acc[3].y);
  *(u32x4*)(dp + lane*4) = w;
  ((h16*)dp)[512 + lane] = __float2half_rn(acct);
}

// ---------------- Chebyshev: plane(2+2s) = 2*S_s@plane(1+2s) - plane0 -
__global__ __launch_bounds__(256) void k_cheb(
    unsigned int* __restrict__ XAu, const int* __restrict__ cols,
    const float* __restrict__ vals, const int* __restrict__ cnt)
{
  const int cc = blockIdx.x;
  const int lane = threadIdx.x & 63;
  const int rr = blockIdx.y*4 + (threadIdx.x >> 6);
  const int r  = __builtin_amdgcn_readfirstlane(rr);
  const int s  = (r >= N_NODES) ? 1 : 0;
  const int n  = r - s*N_NODES;
  int c = cnt[r]; if (c > ELLW) c = ELLW;
  const int*   cp = cols + (size_t)r*ELLW;
  const float* vp = vals + (size_t)r*ELLW;
  const unsigned int* slice = XAu + (size_t)cc*SLICE_DW + PLANE_OFF(1 + 2*s);
  const int sh = (lane & 1) * 16;
  float2 acc[4];
  float  acct = 0.f;
  #pragma unroll
  for (int i = 0; i < 4; ++i) acc[i] = make_float2(0.f, 0.f);
  if (c > 0) {
    int j0 = cp[0];
    const unsigned int* p = slice + (size_t)j0*NSTRIDE;
    u32x4 q = *(const u32x4*)(p + lane*4);
    unsigned int te = p[256 + (lane >> 1)] >> sh;
    for (int k = 0; k < c; ++k) {
      float v = vp[k];
      int kn = (k + 1 < c) ? k + 1 : k;
      int jn = cp[kn];
      const unsigned int* pn = slice + (size_t)jn*NSTRIDE;
      u32x4 nq = *(const u32x4*)(pn + lane*4);
      unsigned int nte = pn[256 + (lane >> 1)] >> sh;
      fma4t(v, q, te, acc, acct);
      q = nq; te = nte;
    }
  }
  // x0 (plane 0), same lane mapping
  const unsigned int* xp = XAu + (size_t)cc*SLICE_DW + (size_t)n*NSTRIDE;
  u32x4 x0 = *(const u32x4*)(xp + lane*4);
  float xt = h16lo(xp[256 + (lane >> 1)] >> sh);
  unsigned int* dp = XAu + (size_t)cc*SLICE_DW + (size_t)n*NSTRIDE
                   + PLANE_OFF(2 + 2*s);
  float2 f;
  u32x4 w;
  f = u2f2(x0[0]); w[0] = packh(2.f*acc[0].x - f.x, 2.f*acc[0].y - f.y);
  f = u2f2(x0[1]); w[1] = packh(2.f*acc[1].x - f.x, 2.f*acc[1].y - f.y);
  f = u2f2(x0[2]); w[2] = packh(2.f*acc[2].x - f.x, 2.f*acc[2].y - f.y);
  f = u2f2(x0[3]); w[3] = packh(2.f*acc[3].x - f.x, 2.f*acc[3].y - f.y);
  __builtin_nontemporal_store(w, (u32x4*)(dp + lane*4));
  ((h16*)dp)[512 + lane] = __float2half_rn(2.f*acct - xt);
}

// ---------------- projection via MFMA, W in LDS, 2 nodes/block -------
// 512 threads = 8 waves. Waves 0-3 own node 2*blk, waves 4-7 own node
// 2*blk+1 (concurrent). Wave wq owns b-rows [16wq,16wq+16). A-frags in
// regs across both stages; acc[0..7] statically indexed.
// mode 0: RHX[n][b][o] = sig(r)*hx (fp16), VALU[n][b][o] = sig(u) (fp16)
// mode 1: out = u*hx + (1-u)*tanh(acc+bias) fp32 (o in [0,64), 1 stage)
__global__ __launch_bounds__(512, 4) void k_projm(
    const unsigned int* __restrict__ XAu, const h16* __restrict__ Wz,
    const float* __restrict__ bias, h16* __restrict__ VALu,
    h16* __restrict__ RHXp, const float* __restrict__ hx,
    float* __restrict__ out, int mode)
{
  __shared__ h16 WL[4*12*64*8];            // 49,152 B
  const int t = threadIdx.x;
  const int w8 = t >> 6;                   // wave 0..7
  const int lane = t & 63;
  const int ni = w8 >> 2;                  // node slot 0/1
  const int wq = w8 & 3;                   // quad-wave within node
  const int quad = lane >> 4, lr = lane & 15;
  const int b0 = wq*16;
  const int cc = 2*wq + (lr >> 3), bs = lr & 7;
  const int n = blockIdx.x*2 + ni;

  // A fragments: read once, keep in registers across both stages.
  const h16* abase = (const h16*)(XAu + (size_t)cc*SLICE_DW + (size_t)n*NSTRIDE)
                   + bs*8 + quad*64;
  f16x8 a[12];
  #pragma unroll
  for (int k0 = 0; k0 < 12; ++k0) a[k0] = *(const f16x8*)(abase + k0*256);

  f32x4 acc[8];
  #pragma unroll
  for (int i = 0; i < 8; ++i) acc[i] = (f32x4){0.f,0.f,0.f,0.f};

  // ---- stage 0 (o in [0,64)) ----
  {
    uint4* dl = (uint4*)WL;
    const uint4* sg = (const uint4*)Wz;
    #pragma unroll
    for (int i = 0; i < 6; ++i) dl[t + i*512] = sg[t + i*512];
  }
  __syncthreads();
  #pragma unroll
  for (int k0 = 0; k0 < 12; ++k0) {
    #pragma unroll
    for (int ot = 0; ot < 4; ++ot) {
      f16x8 bf = *(const f16x8*)(WL + ((ot*12 + k0)*64 + lane)*8);
      acc[ot] = __builtin_amdgcn_mfma_f32_16x16x32_f16(a[k0], bf, acc[ot], 0, 0, 0);
    }
  }

  // ---- stage 1 (o in [64,128)), mode 0 only ----
  if (mode == 0) {
    __syncthreads();                       // stage-0 readers done
    {
      uint4* dl = (uint4*)WL;
      const uint4* sg = (const uint4*)Wz + 3072;
      #pragma unroll
      for (int i = 0; i < 6; ++i) dl[t + i*512] = sg[t + i*512];
    }
    __syncthreads();
    #pragma unroll
    for (int k0 = 0; k0 < 12; ++k0) {
      #pragma unroll
      for (int ot = 0; ot < 4; ++ot) {
        f16x8 bf = *(const f16x8*)(WL + ((ot*12 + k0)*64 + lane)*8);
        acc[4+ot] = __builtin_amdgcn_mfma_f32_16x16x32_f16(a[k0], bf, acc[4+ot], 0, 0, 0);
      }
    }

    // epilogue mode 0: r premultiplied with hx, u stored compact
    #pragma unroll
    for (int ot = 0; ot < 4; ++ot) {
      int o = ot*16 + lr;
      float biaR = bias[o];
      float biaU = bias[64 + o];
      #pragma unroll
      for (int r = 0; r < 4; ++r) {
        int b = b0 + quad*4 + r;
        float rg = fsigmoid(acc[ot][r] + biaR);
        float hv = hx[(size_t)b*(N_NODES*64) + n*64 + o];
        RHXp[(size_t)n*4096 + b*64 + o] = __float2half_rn(rg * hv);
        VALu[(size_t)n*4096 + b*64 + o] =
          __float2half_rn(fsigmoid(acc[4+ot][r] + biaU));
      }
    }
  } else {
    // epilogue mode 1
    #pragma unroll
    for (int ot = 0; ot < 4; ++ot) {
      int o = ot*16 + lr;
      float bia = bias[o];
      #pragma unroll
      for (int r = 0; r < 4; ++r) {
        int b = b0 + quad*4 + r;
        float cv = ftanh(acc[ot][r] + bia);
        float u  = __half2float(VALu[(size_t)n*4096 + b*64 + o]);
        float h  = hx[(size_t)b*(N_NODES*64) + n*64 + o];
        out[(size_t)b*(N_NODES*64) + n*64 + o] = u*h + (1.f - u)*cv;
      }
    }
  }
}

extern "C" void kernel_launch(void* const* d_in, const int* in_sizes, int n_in,
                              void* d_out, int out_size, void* d_ws, size_t ws_size,
                              hipStream_t stream)
{
  const float* inp      = (const float*)d_in[0];
  const float* hx       = (const float*)d_in[1];
  const float* supp     = (const float*)d_in[2];
  const float* mu_w_ru  = (const float*)d_in[3];
  const float* ls_w_ru  = (const float*)d_in[4];
  const float* mu_b_ru  = (const float*)d_in[5];
  const float* ls_b_ru  = (const float*)d_in[6];
  const float* eps_w_ru = (const float*)d_in[7];
  const float* eps_b_ru = (const float*)d_in[8];
  const float* mu_w_c   = (const float*)d_in[9];
  const float* ls_w_c   = (const float*)d_in[10];
  const float* mu_b_c   = (const float*)d_in[11];
  const float* ls_b_c   = (const float*)d_in[12];
  const float* eps_w_c  = (const float*)d_in[13];
  const float* eps_b_c  = (const float*)d_in[14];
  float* out = (float*)d_out;

  char* wsp = (char*)d_ws;
  size_t off = 0;
  auto take = [&](size_t bytes) -> void* {
    void* p = wsp + off;
    off = (off + bytes + 255) & ~(size_t)255;
    return p;
  };
  unsigned int* XAu = (unsigned int*)take(8*SLICE_DW*sizeof(unsigned int)); // 98.3 MB
  h16*   VALU= (h16*)  take((size_t)N_NODES*4096*sizeof(h16));       // 16.4 MB
  h16*   RHX = (h16*)  take((size_t)N_NODES*4096*sizeof(h16));       // 16.4 MB
  h16*   Wzru= (h16*)  take((size_t)8*12*64*8*sizeof(h16));          // 98.3 KB
  h16*   Wzc = (h16*)  take((size_t)4*12*64*8*sizeof(h16));          // 49.2 KB
  float* bru = (float*)take(128*sizeof(float));
  float* bc  = (float*)take(64*sizeof(float));
  int*   ellc= (int*)  take((size_t)2*N_NODES*ELLW*sizeof(int));     // 2.05 MB
  float* ellv= (float*)take((size_t)2*N_NODES*ELLW*sizeof(float));   // 2.05 MB
  int*   cnt = (int*)  take((size_t)2*N_NODES*sizeof(int));
  // total ~135.3 MB
  (void)ws_size;

  hipMemsetAsync(cnt, 0, (size_t)2*N_NODES*sizeof(int), stream);
  k_weights<<<289, 256, 0, stream>>>(mu_w_ru, ls_w_ru, eps_w_ru,
                                     mu_b_ru, ls_b_ru, eps_b_ru,
                                     mu_w_c, ls_w_c, eps_w_c,
                                     mu_b_c, ls_b_c, eps_b_c,
                                     Wzru, bru, Wzc, bc);
  k_ell<<<dim3(8, N_NODES, 2), 256, 0, stream>>>(supp, ellc, ellv, cnt);

  for (int pass = 0; pass < 2; ++pass) {
    k_build0<<<N_NODES, 256, 0, stream>>>(inp, hx, RHX, XAu, pass);
    k_spmm <<<dim3(8, 1000), 256, 0, stream>>>(XAu, ellc, ellv, cnt);
    k_cheb <<<dim3(8, 1000), 256, 0, stream>>>(XAu, ellc, ellv, cnt);
    if (pass == 0)
      k_projm<<<N_NODES/2, 512, 0, stream>>>(XAu, Wzru, bru, VALU, RHX,
                                             hx, nullptr, 0);
    else
      k_projm<<<N_NODES/2, 512, 0, stream>>>(XAu, Wzc, bc, VALU, nullptr,
                                             hx, out, 1);
  }
}